// Round 1
// baseline (4203.698 us; speedup 1.0000x reference)
//
#include <hip/hip_runtime.h>
#include <hip/hip_bf16.h>
#include <math.h>

#define N_NODES 50000
#define NF1 128
#define NF2 64
#define NEDGE 1600000
#define BN_EPS 1e-5f

// ---------------------------------------------------------------------------
// GEMM1: C[N,128] = X[N,128] @ W[128,128]   (f32, VALU)
// Block: 256 threads, 32 rows per block. K tiled by 64 (LDS = 32+16 = 48KB).
// ---------------------------------------------------------------------------
__global__ __launch_bounds__(256) void gemm1_kernel(
    const float4* __restrict__ X4, const float4* __restrict__ W4,
    float* __restrict__ C) {
  __shared__ float4 sW[64 * 32];   // 64 k-rows x 128 cols  (32KB)
  __shared__ float4 sX[32 * 32];   // 32 rows x 128 k       (16KB)
  float* Xl = (float*)sX;
  const int t = threadIdx.x;
  const int r0 = blockIdx.x * 32;

  // stage X tile (full K)
  for (int i = t; i < 1024; i += 256) {
    int rr = i >> 5;
    int r = r0 + rr;
    sX[i] = (r < N_NODES) ? X4[(long)r * 32 + (i & 31)]
                          : make_float4(0.f, 0.f, 0.f, 0.f);
  }

  const int tx = t & 31;   // col group: cols tx*4 .. tx*4+3
  const int ty = t >> 5;   // row group: rows ty*4 .. ty*4+3
  float acc[4][4] = {{0.f}};

  for (int kt = 0; kt < 2; ++kt) {
    __syncthreads();
    // stage W k-tile: k in [kt*64, kt*64+64)
    for (int i = t; i < 2048; i += 256) sW[i] = W4[kt * 2048 + i];
    __syncthreads();
    const int kbase = kt * 64;
#pragma unroll 8
    for (int kk = 0; kk < 64; ++kk) {
      float4 wv = sW[kk * 32 + tx];
      float x0 = Xl[(ty * 4 + 0) * 128 + kbase + kk];
      float x1 = Xl[(ty * 4 + 1) * 128 + kbase + kk];
      float x2 = Xl[(ty * 4 + 2) * 128 + kbase + kk];
      float x3 = Xl[(ty * 4 + 3) * 128 + kbase + kk];
      acc[0][0] += x0 * wv.x; acc[0][1] += x0 * wv.y;
      acc[0][2] += x0 * wv.z; acc[0][3] += x0 * wv.w;
      acc[1][0] += x1 * wv.x; acc[1][1] += x1 * wv.y;
      acc[1][2] += x1 * wv.z; acc[1][3] += x1 * wv.w;
      acc[2][0] += x2 * wv.x; acc[2][1] += x2 * wv.y;
      acc[2][2] += x2 * wv.z; acc[2][3] += x2 * wv.w;
      acc[3][0] += x3 * wv.x; acc[3][1] += x3 * wv.y;
      acc[3][2] += x3 * wv.z; acc[3][3] += x3 * wv.w;
    }
  }
  for (int j = 0; j < 4; ++j) {
    int r = r0 + ty * 4 + j;
    if (r < N_NODES)
      *(float4*)&C[(long)r * 128 + tx * 4] =
          make_float4(acc[j][0], acc[j][1], acc[j][2], acc[j][3]);
  }
}

// ---------------------------------------------------------------------------
// GEMM2: C[N,64] = relu(bn1(H[N,128])) @ W[128,64]
// BN coefficients finalized from raw sums (s1,ss1) in-kernel; fused into the
// X-tile staging load. LDS = 32 + 16 + 1 = 49KB.
// ---------------------------------------------------------------------------
__global__ __launch_bounds__(256) void gemm2_kernel(
    const float4* __restrict__ H4, const float4* __restrict__ W4,
    const float* __restrict__ s1, const float* __restrict__ ss1,
    const float* __restrict__ gamma, const float* __restrict__ beta,
    float* __restrict__ C) {
  __shared__ float4 sW[128 * 16];  // 128 k x 64 cols (32KB)
  __shared__ float4 sX[32 * 32];   // 16KB
  __shared__ float sA[128], sB[128];
  const int t = threadIdx.x;

  if (t < 128) {
    float mean = s1[t] * (1.0f / N_NODES);
    float var = ss1[t] * (1.0f / N_NODES) - mean * mean;
    float a = gamma[t] * rsqrtf(var + BN_EPS);
    sA[t] = a;
    sB[t] = beta[t] - a * mean;
  }
  for (int i = t; i < 2048; i += 256) sW[i] = W4[i];
  __syncthreads();

  const int r0 = blockIdx.x * 32;
  for (int i = t; i < 1024; i += 256) {
    int rr = i >> 5;
    int r = r0 + rr;
    int c4 = i & 31;
    float4 v = make_float4(0.f, 0.f, 0.f, 0.f);
    if (r < N_NODES) {
      v = H4[(long)r * 32 + c4];
      float4 a4 = *(const float4*)&sA[c4 * 4];
      float4 b4 = *(const float4*)&sB[c4 * 4];
      v.x = fmaxf(a4.x * v.x + b4.x, 0.f);
      v.y = fmaxf(a4.y * v.y + b4.y, 0.f);
      v.z = fmaxf(a4.z * v.z + b4.z, 0.f);
      v.w = fmaxf(a4.w * v.w + b4.w, 0.f);
    }
    sX[i] = v;
  }
  __syncthreads();

  const int tx = t & 15;  // cols tx*4..+3 (64 cols)
  const int ty = t >> 4;  // rows ty*2, ty*2+1 (32 rows)
  float acc[2][4] = {{0.f}};
  float* Xl = (float*)sX;
#pragma unroll 8
  for (int k = 0; k < 128; ++k) {
    float4 wv = sW[k * 16 + tx];
    float x0 = Xl[(ty * 2 + 0) * 128 + k];
    float x1 = Xl[(ty * 2 + 1) * 128 + k];
    acc[0][0] += x0 * wv.x; acc[0][1] += x0 * wv.y;
    acc[0][2] += x0 * wv.z; acc[0][3] += x0 * wv.w;
    acc[1][0] += x1 * wv.x; acc[1][1] += x1 * wv.y;
    acc[1][2] += x1 * wv.z; acc[1][3] += x1 * wv.w;
  }
  for (int j = 0; j < 2; ++j) {
    int r = r0 + ty * 2 + j;
    if (r < N_NODES)
      *(float4*)&C[(long)r * 64 + tx * 4] =
          make_float4(acc[j][0], acc[j][1], acc[j][2], acc[j][3]);
  }
}

// ---------------------------------------------------------------------------
// SpMM scatter: H[row[e], :] += vals[e] * S[col[e], :]
// SH = log2(features/4): 5 for 128 feats, 4 for 64 feats.
// One thread per (edge, float4-of-row). Atomic f32 adds.
// ---------------------------------------------------------------------------
template <int SH>
__global__ __launch_bounds__(256) void spmm_kernel(
    const int* __restrict__ row, const int* __restrict__ col,
    const float* __restrict__ vals, const float4* __restrict__ S,
    float* __restrict__ H) {
  unsigned gid = blockIdx.x * 256u + threadIdx.x;
  unsigned e = gid >> SH;
  unsigned j = gid & ((1u << SH) - 1u);
  if (e >= NEDGE) return;
  int r = row[e];
  int c = col[e];
  float v = vals[e];
  float4 s = S[((unsigned)c << SH) + j];
  float* dst = H + (((unsigned long long)r) << (SH + 2)) + j * 4;
  atomicAdd(dst + 0, v * s.x);
  atomicAdd(dst + 1, v * s.y);
  atomicAdd(dst + 2, v * s.z);
  atomicAdd(dst + 3, v * s.w);
}

// ---------------------------------------------------------------------------
// Column stats: s[c] += sum_r H[r][c], ss[c] += sum_r H[r][c]^2
// ---------------------------------------------------------------------------
template <int NF>
__global__ __launch_bounds__(256) void stats_kernel(
    const float* __restrict__ H, float* __restrict__ s,
    float* __restrict__ ss) {
  const int t = threadIdx.x;
  const int c = t & (NF - 1);
  const int rg = t / NF;
  const int RG = 256 / NF;
  float sum = 0.f, sq = 0.f;
  for (int r = blockIdx.x * RG + rg; r < N_NODES; r += gridDim.x * RG) {
    float x = H[(long)r * NF + c];
    sum += x;
    sq += x * x;
  }
  atomicAdd(&s[c], sum);
  atomicAdd(&ss[c], sq);
}

// ---------------------------------------------------------------------------
// Final: acc[c] += sum_r relu(bn2(H2[r][c])) * Wm[r][c]
// ---------------------------------------------------------------------------
__global__ __launch_bounds__(256) void final_kernel(
    const float* __restrict__ H, const float* __restrict__ Wm,
    const float* __restrict__ s2, const float* __restrict__ ss2,
    const float* __restrict__ gamma, const float* __restrict__ beta,
    float* __restrict__ acc) {
  const int t = threadIdx.x;
  const int c = t & 63;
  const int rg = t >> 6;  // 0..3
  float mean = s2[c] * (1.0f / N_NODES);
  float var = ss2[c] * (1.0f / N_NODES) - mean * mean;
  float a = gamma[c] * rsqrtf(var + BN_EPS);
  float b = beta[c] - a * mean;
  float sum = 0.f;
  for (int r = blockIdx.x * 4 + rg; r < N_NODES; r += gridDim.x * 4) {
    float x = fmaxf(a * H[(long)r * 64 + c] + b, 0.f);
    sum += x * Wm[(long)r * 64 + c];
  }
  __shared__ float red[256];
  red[t] = sum;
  __syncthreads();
  if (t < 128) red[t] += red[t + 128];
  __syncthreads();
  if (t < 64) atomicAdd(&acc[c], red[t] + red[t + 64]);
}

__global__ void writeout_kernel(const float* __restrict__ acc,
                                const float* __restrict__ bm,
                                float* __restrict__ out) {
  int t = threadIdx.x;
  if (t < 64) {
    float x = acc[t] + bm[t];
    out[t] = 1.0f / (1.0f + expf(-x));
  }
}

// ---------------------------------------------------------------------------
extern "C" void kernel_launch(void* const* d_in, const int* in_sizes, int n_in,
                              void* d_out, int out_size, void* d_ws,
                              size_t ws_size, hipStream_t stream) {
  const float* emb  = (const float*)d_in[0];
  const float* W1   = (const float*)d_in[1];
  // d_in[2] = b1: cancels exactly under BN ((x+b)-mean(x+b) = x-mean)
  const float* g1   = (const float*)d_in[3];
  const float* be1  = (const float*)d_in[4];
  const float* W2   = (const float*)d_in[5];
  // d_in[6] = b2: cancels under BN
  const float* g2   = (const float*)d_in[7];
  const float* be2  = (const float*)d_in[8];
  const float* Wm   = (const float*)d_in[9];
  const float* bm   = (const float*)d_in[10];
  // d_in[11] = vertices = arange(N): identity gather
  const int* row    = (const int*)d_in[12];
  const int* col    = (const int*)d_in[13];
  const float* vals = (const float*)d_in[14];

  // workspace layout (floats): support 6.4M | h 6.4M | stats 448
  float* support = (float*)d_ws;
  float* h   = support + 6400000;
  float* s1  = h + 6400000;
  float* ss1 = s1 + 128;
  float* s2  = ss1 + 128;
  float* ss2 = s2 + 64;
  float* acc = ss2 + 64;
  float* out = (float*)d_out;

  // zero accumulators (every call — deterministic across graph replays)
  hipMemsetAsync(h, 0, 6400000 * sizeof(float), stream);
  hipMemsetAsync(s1, 0, 448 * sizeof(float), stream);

  // Layer 1
  gemm1_kernel<<<1563, 256, 0, stream>>>((const float4*)emb,
                                         (const float4*)W1, support);
  spmm_kernel<5><<<(NEDGE * 32) / 256, 256, 0, stream>>>(
      row, col, vals, (const float4*)support, h);
  stats_kernel<128><<<512, 256, 0, stream>>>(h, s1, ss1);

  // Layer 2 (BN1+ReLU fused into GEMM2 input staging)
  gemm2_kernel<<<1563, 256, 0, stream>>>((const float4*)h, (const float4*)W2,
                                         s1, ss1, g1, be1, support);
  hipMemsetAsync(h, 0, 3200000 * sizeof(float), stream);  // h2 reuses h region
  spmm_kernel<4><<<(NEDGE * 16) / 256, 256, 0, stream>>>(
      row, col, vals, (const float4*)support, h);
  stats_kernel<64><<<512, 256, 0, stream>>>(h, s2, ss2);

  // MaskLinear + sigmoid
  final_kernel<<<512, 256, 0, stream>>>(h, Wm, s2, ss2, g2, be2, acc);
  writeout_kernel<<<1, 64, 0, stream>>>(acc, bm, out);
}

// Round 2
// 746.978 us; speedup vs baseline: 5.6276x; 5.6276x over previous
//
#include <hip/hip_runtime.h>
#include <hip/hip_bf16.h>
#include <math.h>

#define N_NODES 50000
#define NEDGE 1600000
#define BN_EPS 1e-5f

// ---------------------------------------------------------------------------
// GEMM1: C[N,128] = X[N,128] @ W[128,128]   (f32, VALU)
// ---------------------------------------------------------------------------
__global__ __launch_bounds__(256) void gemm1_kernel(
    const float4* __restrict__ X4, const float4* __restrict__ W4,
    float* __restrict__ C) {
  __shared__ float4 sW[64 * 32];   // 64 k-rows x 128 cols  (32KB)
  __shared__ float4 sX[32 * 32];   // 32 rows x 128 k       (16KB)
  float* Xl = (float*)sX;
  const int t = threadIdx.x;
  const int r0 = blockIdx.x * 32;

  for (int i = t; i < 1024; i += 256) {
    int rr = i >> 5;
    int r = r0 + rr;
    sX[i] = (r < N_NODES) ? X4[(long)r * 32 + (i & 31)]
                          : make_float4(0.f, 0.f, 0.f, 0.f);
  }

  const int tx = t & 31;
  const int ty = t >> 5;
  float acc[4][4] = {{0.f}};

  for (int kt = 0; kt < 2; ++kt) {
    __syncthreads();
    for (int i = t; i < 2048; i += 256) sW[i] = W4[kt * 2048 + i];
    __syncthreads();
    const int kbase = kt * 64;
#pragma unroll 8
    for (int kk = 0; kk < 64; ++kk) {
      float4 wv = sW[kk * 32 + tx];
      float x0 = Xl[(ty * 4 + 0) * 128 + kbase + kk];
      float x1 = Xl[(ty * 4 + 1) * 128 + kbase + kk];
      float x2 = Xl[(ty * 4 + 2) * 128 + kbase + kk];
      float x3 = Xl[(ty * 4 + 3) * 128 + kbase + kk];
      acc[0][0] += x0 * wv.x; acc[0][1] += x0 * wv.y;
      acc[0][2] += x0 * wv.z; acc[0][3] += x0 * wv.w;
      acc[1][0] += x1 * wv.x; acc[1][1] += x1 * wv.y;
      acc[1][2] += x1 * wv.z; acc[1][3] += x1 * wv.w;
      acc[2][0] += x2 * wv.x; acc[2][1] += x2 * wv.y;
      acc[2][2] += x2 * wv.z; acc[2][3] += x2 * wv.w;
      acc[3][0] += x3 * wv.x; acc[3][1] += x3 * wv.y;
      acc[3][2] += x3 * wv.z; acc[3][3] += x3 * wv.w;
    }
  }
  for (int j = 0; j < 4; ++j) {
    int r = r0 + ty * 4 + j;
    if (r < N_NODES)
      *(float4*)&C[(long)r * 128 + tx * 4] =
          make_float4(acc[j][0], acc[j][1], acc[j][2], acc[j][3]);
  }
}

// ---------------------------------------------------------------------------
// GEMM2: C[N,64] = relu(bn1(H[N,128])) @ W[128,64]  (BN fused into staging)
// ---------------------------------------------------------------------------
__global__ __launch_bounds__(256) void gemm2_kernel(
    const float4* __restrict__ H4, const float4* __restrict__ W4,
    const float* __restrict__ s1, const float* __restrict__ ss1,
    const float* __restrict__ gamma, const float* __restrict__ beta,
    float* __restrict__ C) {
  __shared__ float4 sW[128 * 16];  // 32KB
  __shared__ float4 sX[32 * 32];   // 16KB
  __shared__ float sA[128], sB[128];
  const int t = threadIdx.x;

  if (t < 128) {
    float mean = s1[t] * (1.0f / N_NODES);
    float var = ss1[t] * (1.0f / N_NODES) - mean * mean;
    float a = gamma[t] * rsqrtf(var + BN_EPS);
    sA[t] = a;
    sB[t] = beta[t] - a * mean;
  }
  for (int i = t; i < 2048; i += 256) sW[i] = W4[i];
  __syncthreads();

  const int r0 = blockIdx.x * 32;
  for (int i = t; i < 1024; i += 256) {
    int rr = i >> 5;
    int r = r0 + rr;
    int c4 = i & 31;
    float4 v = make_float4(0.f, 0.f, 0.f, 0.f);
    if (r < N_NODES) {
      v = H4[(long)r * 32 + c4];
      float4 a4 = *(const float4*)&sA[c4 * 4];
      float4 b4 = *(const float4*)&sB[c4 * 4];
      v.x = fmaxf(a4.x * v.x + b4.x, 0.f);
      v.y = fmaxf(a4.y * v.y + b4.y, 0.f);
      v.z = fmaxf(a4.z * v.z + b4.z, 0.f);
      v.w = fmaxf(a4.w * v.w + b4.w, 0.f);
    }
    sX[i] = v;
  }
  __syncthreads();

  const int tx = t & 15;
  const int ty = t >> 4;
  float acc[2][4] = {{0.f}};
  float* Xl = (float*)sX;
#pragma unroll 8
  for (int k = 0; k < 128; ++k) {
    float4 wv = sW[k * 16 + tx];
    float x0 = Xl[(ty * 2 + 0) * 128 + k];
    float x1 = Xl[(ty * 2 + 1) * 128 + k];
    acc[0][0] += x0 * wv.x; acc[0][1] += x0 * wv.y;
    acc[0][2] += x0 * wv.z; acc[0][3] += x0 * wv.w;
    acc[1][0] += x1 * wv.x; acc[1][1] += x1 * wv.y;
    acc[1][2] += x1 * wv.z; acc[1][3] += x1 * wv.w;
  }
  for (int j = 0; j < 2; ++j) {
    int r = r0 + ty * 2 + j;
    if (r < N_NODES)
      *(float4*)&C[(long)r * 64 + tx * 4] =
          make_float4(acc[j][0], acc[j][1], acc[j][2], acc[j][3]);
  }
}

// ---------------------------------------------------------------------------
// CSR build: histogram -> scan -> scatter (counting sort of edges by row)
// ---------------------------------------------------------------------------
__global__ __launch_bounds__(256) void hist_kernel(const int* __restrict__ row,
                                                   int* __restrict__ cnt) {
  int e = blockIdx.x * 256 + threadIdx.x;
  if (e < NEDGE) atomicAdd(&cnt[row[e]], 1);
}

__global__ __launch_bounds__(1024) void scan_kernel(
    const int* __restrict__ cnt, int* __restrict__ rowptr,
    int* __restrict__ cursor) {
  const int CH = 49;  // 1024*49 = 50176 >= 50000
  const int t = threadIdx.x;
  const int base = t * CH;
  int local = 0;
  for (int i = 0; i < CH; ++i) {
    int idx = base + i;
    if (idx < N_NODES) local += cnt[idx];
  }
  __shared__ int part[1024];
  part[t] = local;
  __syncthreads();
  for (int off = 1; off < 1024; off <<= 1) {
    int v = (t >= off) ? part[t - off] : 0;
    __syncthreads();
    part[t] += v;
    __syncthreads();
  }
  int prefix = (t == 0) ? 0 : part[t - 1];
  for (int i = 0; i < CH; ++i) {
    int idx = base + i;
    if (idx < N_NODES) {
      rowptr[idx] = prefix;
      cursor[idx] = prefix;
      prefix += cnt[idx];
    }
  }
  if (t == 1023) rowptr[N_NODES] = prefix;
}

__global__ __launch_bounds__(256) void scatter_kernel(
    const int* __restrict__ row, const int* __restrict__ col,
    const float* __restrict__ vals, int* __restrict__ cursor,
    int* __restrict__ ecol, float* __restrict__ eval) {
  int e = blockIdx.x * 256 + threadIdx.x;
  if (e < NEDGE) {
    int p = atomicAdd(&cursor[row[e]], 1);
    ecol[p] = col[e];
    eval[p] = vals[e];
  }
}

// ---------------------------------------------------------------------------
// Gather-SpMM, 128 feats: one wave per row, float2 per lane. No atomics.
// ---------------------------------------------------------------------------
__global__ __launch_bounds__(256) void gather128_kernel(
    const int* __restrict__ rowptr, const int* __restrict__ ecol,
    const float* __restrict__ eval, const float2* __restrict__ S,
    float2* __restrict__ H) {
  int r = (blockIdx.x * 256 + threadIdx.x) >> 6;
  int lane = threadIdx.x & 63;
  if (r >= N_NODES) return;
  int b = rowptr[r], e2 = rowptr[r + 1];
  float2 a0 = make_float2(0.f, 0.f), a1 = make_float2(0.f, 0.f);
  int e = b;
  for (; e + 1 < e2; e += 2) {
    int c0 = ecol[e], c1 = ecol[e + 1];
    float v0 = eval[e], v1 = eval[e + 1];
    float2 s0 = S[(long)c0 * 64 + lane];
    float2 s1 = S[(long)c1 * 64 + lane];
    a0.x += v0 * s0.x; a0.y += v0 * s0.y;
    a1.x += v1 * s1.x; a1.y += v1 * s1.y;
  }
  if (e < e2) {
    int c0 = ecol[e];
    float v0 = eval[e];
    float2 s0 = S[(long)c0 * 64 + lane];
    a0.x += v0 * s0.x; a0.y += v0 * s0.y;
  }
  H[(long)r * 64 + lane] = make_float2(a0.x + a1.x, a0.y + a1.y);
}

// ---------------------------------------------------------------------------
// Gather-SpMM, 64 feats: one wave per row, 1 float per lane.
// ---------------------------------------------------------------------------
__global__ __launch_bounds__(256) void gather64_kernel(
    const int* __restrict__ rowptr, const int* __restrict__ ecol,
    const float* __restrict__ eval, const float* __restrict__ S,
    float* __restrict__ H) {
  int r = (blockIdx.x * 256 + threadIdx.x) >> 6;
  int lane = threadIdx.x & 63;
  if (r >= N_NODES) return;
  int b = rowptr[r], e2 = rowptr[r + 1];
  float a0 = 0.f, a1 = 0.f;
  int e = b;
  for (; e + 1 < e2; e += 2) {
    int c0 = ecol[e], c1 = ecol[e + 1];
    float v0 = eval[e], v1 = eval[e + 1];
    a0 += v0 * S[(long)c0 * 64 + lane];
    a1 += v1 * S[(long)c1 * 64 + lane];
  }
  if (e < e2) a0 += eval[e] * S[(long)ecol[e] * 64 + lane];
  H[(long)r * 64 + lane] = a0 + a1;
}

// ---------------------------------------------------------------------------
// Column stats: s[c] += sum_r H[r][c], ss[c] += sum_r H[r][c]^2
// ---------------------------------------------------------------------------
template <int NF>
__global__ __launch_bounds__(256) void stats_kernel(
    const float* __restrict__ H, float* __restrict__ s,
    float* __restrict__ ss) {
  const int t = threadIdx.x;
  const int c = t & (NF - 1);
  const int rg = t / NF;
  const int RG = 256 / NF;
  float sum = 0.f, sq = 0.f;
  for (int r = blockIdx.x * RG + rg; r < N_NODES; r += gridDim.x * RG) {
    float x = H[(long)r * NF + c];
    sum += x;
    sq += x * x;
  }
  atomicAdd(&s[c], sum);
  atomicAdd(&ss[c], sq);
}

// ---------------------------------------------------------------------------
// Final: acc[c] += sum_r relu(bn2(H2[r][c])) * Wm[r][c]
// ---------------------------------------------------------------------------
__global__ __launch_bounds__(256) void final_kernel(
    const float* __restrict__ H, const float* __restrict__ Wm,
    const float* __restrict__ s2, const float* __restrict__ ss2,
    const float* __restrict__ gamma, const float* __restrict__ beta,
    float* __restrict__ acc) {
  const int t = threadIdx.x;
  const int c = t & 63;
  const int rg = t >> 6;
  float mean = s2[c] * (1.0f / N_NODES);
  float var = ss2[c] * (1.0f / N_NODES) - mean * mean;
  float a = gamma[c] * rsqrtf(var + BN_EPS);
  float b = beta[c] - a * mean;
  float sum = 0.f;
  for (int r = blockIdx.x * 4 + rg; r < N_NODES; r += gridDim.x * 4) {
    float x = fmaxf(a * H[(long)r * 64 + c] + b, 0.f);
    sum += x * Wm[(long)r * 64 + c];
  }
  __shared__ float red[256];
  red[t] = sum;
  __syncthreads();
  if (t < 128) red[t] += red[t + 128];
  __syncthreads();
  if (t < 64) atomicAdd(&acc[c], red[t] + red[t + 64]);
}

__global__ void writeout_kernel(const float* __restrict__ acc,
                                const float* __restrict__ bm,
                                float* __restrict__ out) {
  int t = threadIdx.x;
  if (t < 64) {
    float x = acc[t] + bm[t];
    out[t] = 1.0f / (1.0f + expf(-x));
  }
}

// ---------------------------------------------------------------------------
extern "C" void kernel_launch(void* const* d_in, const int* in_sizes, int n_in,
                              void* d_out, int out_size, void* d_ws,
                              size_t ws_size, hipStream_t stream) {
  const float* emb  = (const float*)d_in[0];
  const float* W1   = (const float*)d_in[1];
  // d_in[2] = b1: cancels exactly under BN
  const float* g1   = (const float*)d_in[3];
  const float* be1  = (const float*)d_in[4];
  const float* W2   = (const float*)d_in[5];
  // d_in[6] = b2: cancels under BN
  const float* g2   = (const float*)d_in[7];
  const float* be2  = (const float*)d_in[8];
  const float* Wm   = (const float*)d_in[9];
  const float* bm   = (const float*)d_in[10];
  // d_in[11] = vertices = arange(N): identity gather
  const int* row    = (const int*)d_in[12];
  const int* col    = (const int*)d_in[13];
  const float* vals = (const float*)d_in[14];

  // workspace layout
  float* support = (float*)d_ws;           // 6,400,000 f
  float* h       = support + 6400000;      // 6,400,000 f
  int*   ecol    = (int*)(h + 6400000);    // 1,600,000 i
  float* eval    = (float*)(ecol + 1600000); // 1,600,000 f
  int*   rowptr  = (int*)(eval + 1600000); // 50,001 i
  int*   cursor  = rowptr + 50001;         // 50,000 i
  int*   cnt     = cursor + 50000;         // 50,000 i
  float* s1      = (float*)(cnt + 50000);  // 128
  float* ss1     = s1 + 128;               // 128
  float* s2      = ss1 + 128;              // 64
  float* ss2     = s2 + 64;                // 64
  float* acc     = ss2 + 64;               // 64
  float* out = (float*)d_out;

  // zero: histogram counters + stats accumulators
  hipMemsetAsync(cnt, 0, 50000 * sizeof(int), stream);
  hipMemsetAsync(s1, 0, 448 * sizeof(float), stream);

  // ---- CSR build (counting sort by row) ----
  hist_kernel<<<(NEDGE + 255) / 256, 256, 0, stream>>>(row, cnt);
  scan_kernel<<<1, 1024, 0, stream>>>(cnt, rowptr, cursor);
  scatter_kernel<<<(NEDGE + 255) / 256, 256, 0, stream>>>(row, col, vals,
                                                          cursor, ecol, eval);

  // ---- Layer 1 ----
  gemm1_kernel<<<1563, 256, 0, stream>>>((const float4*)emb,
                                         (const float4*)W1, support);
  gather128_kernel<<<(N_NODES + 3) / 4, 256, 0, stream>>>(
      rowptr, ecol, eval, (const float2*)support, (float2*)h);
  stats_kernel<128><<<512, 256, 0, stream>>>(h, s1, ss1);

  // ---- Layer 2 (BN1+ReLU fused into GEMM2 staging) ----
  gemm2_kernel<<<1563, 256, 0, stream>>>((const float4*)h, (const float4*)W2,
                                         s1, ss1, g1, be1, support);
  gather64_kernel<<<(N_NODES + 3) / 4, 256, 0, stream>>>(
      rowptr, ecol, eval, support, h);
  stats_kernel<64><<<512, 256, 0, stream>>>(h, s2, ss2);

  // ---- MaskLinear + sigmoid ----
  final_kernel<<<512, 256, 0, stream>>>(h, Wm, s2, ss2, g2, be2, acc);
  writeout_kernel<<<1, 64, 0, stream>>>(acc, bm, out);
}

// Round 3
// 541.131 us; speedup vs baseline: 7.7684x; 1.3804x over previous
//
#include <hip/hip_runtime.h>
#include <hip/hip_bf16.h>
#include <math.h>

#define N_NODES 50000
#define NEDGE 1600000
#define BN_EPS 1e-5f

__device__ inline float bf2f(ushort u) {
  union { unsigned i; float f; } v;
  v.i = ((unsigned)u) << 16;
  return v.f;
}
__device__ inline ushort f2bf(float x) {
  __hip_bfloat16 b = __float2bfloat16(x);
  return *(ushort*)&b;
}

// ---------------------------------------------------------------------------
// GEMM1: C[N,128](bf16) = X[N,128] @ W[128,128]   (f32 accum, VALU)
// ---------------------------------------------------------------------------
__global__ __launch_bounds__(256) void gemm1_kernel(
    const float4* __restrict__ X4, const float4* __restrict__ W4,
    ushort* __restrict__ C) {
  __shared__ float4 sW[64 * 32];   // 32KB
  __shared__ float4 sX[32 * 32];   // 16KB
  float* Xl = (float*)sX;
  const int t = threadIdx.x;
  const int r0 = blockIdx.x * 32;

  for (int i = t; i < 1024; i += 256) {
    int rr = i >> 5;
    int r = r0 + rr;
    sX[i] = (r < N_NODES) ? X4[(long)r * 32 + (i & 31)]
                          : make_float4(0.f, 0.f, 0.f, 0.f);
  }

  const int tx = t & 31;
  const int ty = t >> 5;
  float acc[4][4] = {{0.f}};

  for (int kt = 0; kt < 2; ++kt) {
    __syncthreads();
    for (int i = t; i < 2048; i += 256) sW[i] = W4[kt * 2048 + i];
    __syncthreads();
    const int kbase = kt * 64;
#pragma unroll 8
    for (int kk = 0; kk < 64; ++kk) {
      float4 wv = sW[kk * 32 + tx];
      float x0 = Xl[(ty * 4 + 0) * 128 + kbase + kk];
      float x1 = Xl[(ty * 4 + 1) * 128 + kbase + kk];
      float x2 = Xl[(ty * 4 + 2) * 128 + kbase + kk];
      float x3 = Xl[(ty * 4 + 3) * 128 + kbase + kk];
      acc[0][0] += x0 * wv.x; acc[0][1] += x0 * wv.y;
      acc[0][2] += x0 * wv.z; acc[0][3] += x0 * wv.w;
      acc[1][0] += x1 * wv.x; acc[1][1] += x1 * wv.y;
      acc[1][2] += x1 * wv.z; acc[1][3] += x1 * wv.w;
      acc[2][0] += x2 * wv.x; acc[2][1] += x2 * wv.y;
      acc[2][2] += x2 * wv.z; acc[2][3] += x2 * wv.w;
      acc[3][0] += x3 * wv.x; acc[3][1] += x3 * wv.y;
      acc[3][2] += x3 * wv.z; acc[3][3] += x3 * wv.w;
    }
  }
  for (int j = 0; j < 4; ++j) {
    int r = r0 + ty * 4 + j;
    if (r < N_NODES) {
      ushort4 o;
      o.x = f2bf(acc[j][0]); o.y = f2bf(acc[j][1]);
      o.z = f2bf(acc[j][2]); o.w = f2bf(acc[j][3]);
      *(ushort4*)&C[(long)r * 128 + tx * 4] = o;
    }
  }
}

// ---------------------------------------------------------------------------
// GEMM2: C[N,64](bf16) = relu(bn1(H[N,128])) @ W[128,64]
// ---------------------------------------------------------------------------
__global__ __launch_bounds__(256) void gemm2_kernel(
    const float4* __restrict__ H4, const float4* __restrict__ W4,
    const float* __restrict__ s1, const float* __restrict__ ss1,
    const float* __restrict__ gamma, const float* __restrict__ beta,
    ushort* __restrict__ C) {
  __shared__ float4 sW[128 * 16];  // 32KB
  __shared__ float4 sX[32 * 32];   // 16KB
  __shared__ float sA[128], sB[128];
  const int t = threadIdx.x;

  if (t < 128) {
    float mean = s1[t] * (1.0f / N_NODES);
    float var = ss1[t] * (1.0f / N_NODES) - mean * mean;
    float a = gamma[t] * rsqrtf(var + BN_EPS);
    sA[t] = a;
    sB[t] = beta[t] - a * mean;
  }
  for (int i = t; i < 2048; i += 256) sW[i] = W4[i];
  __syncthreads();

  const int r0 = blockIdx.x * 32;
  for (int i = t; i < 1024; i += 256) {
    int rr = i >> 5;
    int r = r0 + rr;
    int c4 = i & 31;
    float4 v = make_float4(0.f, 0.f, 0.f, 0.f);
    if (r < N_NODES) {
      v = H4[(long)r * 32 + c4];
      float4 a4 = *(const float4*)&sA[c4 * 4];
      float4 b4 = *(const float4*)&sB[c4 * 4];
      v.x = fmaxf(a4.x * v.x + b4.x, 0.f);
      v.y = fmaxf(a4.y * v.y + b4.y, 0.f);
      v.z = fmaxf(a4.z * v.z + b4.z, 0.f);
      v.w = fmaxf(a4.w * v.w + b4.w, 0.f);
    }
    sX[i] = v;
  }
  __syncthreads();

  const int tx = t & 15;
  const int ty = t >> 4;
  float acc[2][4] = {{0.f}};
  float* Xl = (float*)sX;
#pragma unroll 8
  for (int k = 0; k < 128; ++k) {
    float4 wv = sW[k * 16 + tx];
    float x0 = Xl[(ty * 2 + 0) * 128 + k];
    float x1 = Xl[(ty * 2 + 1) * 128 + k];
    acc[0][0] += x0 * wv.x; acc[0][1] += x0 * wv.y;
    acc[0][2] += x0 * wv.z; acc[0][3] += x0 * wv.w;
    acc[1][0] += x1 * wv.x; acc[1][1] += x1 * wv.y;
    acc[1][2] += x1 * wv.z; acc[1][3] += x1 * wv.w;
  }
  for (int j = 0; j < 2; ++j) {
    int r = r0 + ty * 2 + j;
    if (r < N_NODES) {
      ushort4 o;
      o.x = f2bf(acc[j][0]); o.y = f2bf(acc[j][1]);
      o.z = f2bf(acc[j][2]); o.w = f2bf(acc[j][3]);
      *(ushort4*)&C[(long)r * 64 + tx * 4] = o;
    }
  }
}

// ---------------------------------------------------------------------------
// CSR build: histogram -> parallel scan -> scatter (int2 payload)
// ---------------------------------------------------------------------------
__global__ __launch_bounds__(256) void hist_kernel(
    const int4* __restrict__ row4, int* __restrict__ cnt) {
  int i = blockIdx.x * 256 + threadIdx.x;
  if (i < NEDGE / 4) {
    int4 r = row4[i];
    atomicAdd(&cnt[r.x], 1);
    atomicAdd(&cnt[r.y], 1);
    atomicAdd(&cnt[r.z], 1);
    atomicAdd(&cnt[r.w], 1);
  }
}

__global__ __launch_bounds__(256) void blocksum_kernel(
    const int* __restrict__ cnt, int* __restrict__ bsum) {
  int idx = blockIdx.x * 256 + threadIdx.x;
  int v = (idx < N_NODES) ? cnt[idx] : 0;
  __shared__ int sc[256];
  sc[threadIdx.x] = v;
  __syncthreads();
  for (int off = 128; off > 0; off >>= 1) {
    if (threadIdx.x < off) sc[threadIdx.x] += sc[threadIdx.x + off];
    __syncthreads();
  }
  if (threadIdx.x == 0) bsum[blockIdx.x] = sc[0];
}

__global__ __launch_bounds__(256) void scanb_kernel(
    const int* __restrict__ bsum, int* __restrict__ boff, int nb) {
  int t = threadIdx.x;
  int v = (t < nb) ? bsum[t] : 0;
  __shared__ int sc[256];
  sc[t] = v;
  __syncthreads();
  for (int off = 1; off < 256; off <<= 1) {
    int x = (t >= off) ? sc[t - off] : 0;
    __syncthreads();
    sc[t] += x;
    __syncthreads();
  }
  if (t < nb) boff[t] = sc[t] - v;  // exclusive
}

__global__ __launch_bounds__(256) void expand_kernel(
    const int* __restrict__ cnt, const int* __restrict__ boff,
    int* __restrict__ rowptr, int* __restrict__ cursor) {
  int t = threadIdx.x;
  int idx = blockIdx.x * 256 + t;
  int v = (idx < N_NODES) ? cnt[idx] : 0;
  __shared__ int sc[256];
  sc[t] = v;
  __syncthreads();
  for (int off = 1; off < 256; off <<= 1) {
    int x = (t >= off) ? sc[t - off] : 0;
    __syncthreads();
    sc[t] += x;
    __syncthreads();
  }
  if (idx < N_NODES) {
    int p = boff[blockIdx.x] + sc[t] - v;
    rowptr[idx] = p;
    cursor[idx] = p;
  }
  if (idx == 0) rowptr[N_NODES] = NEDGE;
}

__global__ __launch_bounds__(256) void scatter_kernel(
    const int4* __restrict__ row4, const int4* __restrict__ col4,
    const float4* __restrict__ vals4, int* __restrict__ cursor,
    int2* __restrict__ epack) {
  int i = blockIdx.x * 256 + threadIdx.x;
  if (i >= NEDGE / 4) return;
  int4 r = row4[i];
  int4 c = col4[i];
  float4 v = vals4[i];
  int p0 = atomicAdd(&cursor[r.x], 1);
  epack[p0] = make_int2(c.x, __float_as_int(v.x));
  int p1 = atomicAdd(&cursor[r.y], 1);
  epack[p1] = make_int2(c.y, __float_as_int(v.y));
  int p2 = atomicAdd(&cursor[r.z], 1);
  epack[p2] = make_int2(c.z, __float_as_int(v.z));
  int p3 = atomicAdd(&cursor[r.w], 1);
  epack[p3] = make_int2(c.w, __float_as_int(v.w));
}

// ---------------------------------------------------------------------------
// Gather-SpMM, 128 feats (bf16 source): one wave per row, ushort2/lane.
// ---------------------------------------------------------------------------
__global__ __launch_bounds__(256) void gather128_kernel(
    const int* __restrict__ rowptr, const int2* __restrict__ epack,
    const ushort* __restrict__ S, float2* __restrict__ H) {
  int r = (blockIdx.x * 256 + threadIdx.x) >> 6;
  int lane = threadIdx.x & 63;
  if (r >= N_NODES) return;
  int b = rowptr[r], e2 = rowptr[r + 1];
  float a0x = 0.f, a0y = 0.f, a1x = 0.f, a1y = 0.f;
  int e = b;
  for (; e + 1 < e2; e += 2) {
    int2 ep0 = epack[e];
    int2 ep1 = epack[e + 1];
    float v0 = __int_as_float(ep0.y);
    float v1 = __int_as_float(ep1.y);
    ushort2 u0 = ((const ushort2*)(S + (long)ep0.x * 128))[lane];
    ushort2 u1 = ((const ushort2*)(S + (long)ep1.x * 128))[lane];
    a0x += v0 * bf2f(u0.x); a0y += v0 * bf2f(u0.y);
    a1x += v1 * bf2f(u1.x); a1y += v1 * bf2f(u1.y);
  }
  if (e < e2) {
    int2 ep0 = epack[e];
    float v0 = __int_as_float(ep0.y);
    ushort2 u0 = ((const ushort2*)(S + (long)ep0.x * 128))[lane];
    a0x += v0 * bf2f(u0.x); a0y += v0 * bf2f(u0.y);
  }
  H[(long)r * 64 + lane] = make_float2(a0x + a1x, a0y + a1y);
}

// ---------------------------------------------------------------------------
// Gather-SpMM, 64 feats (bf16 source): half-wave per row, ushort2/lane.
// ---------------------------------------------------------------------------
__global__ __launch_bounds__(256) void gather64_kernel(
    const int* __restrict__ rowptr, const int2* __restrict__ epack,
    const ushort* __restrict__ S, float2* __restrict__ H) {
  int r = (blockIdx.x * 256 + threadIdx.x) >> 5;
  int sub = threadIdx.x & 31;
  if (r >= N_NODES) return;
  int b = rowptr[r], e2 = rowptr[r + 1];
  float a0x = 0.f, a0y = 0.f, a1x = 0.f, a1y = 0.f;
  int e = b;
  for (; e + 1 < e2; e += 2) {
    int2 ep0 = epack[e];
    int2 ep1 = epack[e + 1];
    float v0 = __int_as_float(ep0.y);
    float v1 = __int_as_float(ep1.y);
    ushort2 u0 = ((const ushort2*)(S + (long)ep0.x * 64))[sub];
    ushort2 u1 = ((const ushort2*)(S + (long)ep1.x * 64))[sub];
    a0x += v0 * bf2f(u0.x); a0y += v0 * bf2f(u0.y);
    a1x += v1 * bf2f(u1.x); a1y += v1 * bf2f(u1.y);
  }
  if (e < e2) {
    int2 ep0 = epack[e];
    float v0 = __int_as_float(ep0.y);
    ushort2 u0 = ((const ushort2*)(S + (long)ep0.x * 64))[sub];
    a0x += v0 * bf2f(u0.x); a0y += v0 * bf2f(u0.y);
  }
  H[(long)r * 32 + sub] = make_float2(a0x + a1x, a0y + a1y);
}

// ---------------------------------------------------------------------------
// Column stats over f32 H
// ---------------------------------------------------------------------------
template <int NF>
__global__ __launch_bounds__(256) void stats_kernel(
    const float* __restrict__ H, float* __restrict__ s,
    float* __restrict__ ss) {
  const int t = threadIdx.x;
  const int c = t & (NF - 1);
  const int rg = t / NF;
  const int RG = 256 / NF;
  float sum = 0.f, sq = 0.f;
  for (int r = blockIdx.x * RG + rg; r < N_NODES; r += gridDim.x * RG) {
    float x = H[(long)r * NF + c];
    sum += x;
    sq += x * x;
  }
  atomicAdd(&s[c], sum);
  atomicAdd(&ss[c], sq);
}

// ---------------------------------------------------------------------------
// Final: acc[c] += sum_r relu(bn2(H2[r][c])) * Wm[r][c]
// ---------------------------------------------------------------------------
__global__ __launch_bounds__(256) void final_kernel(
    const float* __restrict__ H, const float* __restrict__ Wm,
    const float* __restrict__ s2, const float* __restrict__ ss2,
    const float* __restrict__ gamma, const float* __restrict__ beta,
    float* __restrict__ acc) {
  const int t = threadIdx.x;
  const int c = t & 63;
  const int rg = t >> 6;
  float mean = s2[c] * (1.0f / N_NODES);
  float var = ss2[c] * (1.0f / N_NODES) - mean * mean;
  float a = gamma[c] * rsqrtf(var + BN_EPS);
  float b = beta[c] - a * mean;
  float sum = 0.f;
  for (int r = blockIdx.x * 4 + rg; r < N_NODES; r += gridDim.x * 4) {
    float x = fmaxf(a * H[(long)r * 64 + c] + b, 0.f);
    sum += x * Wm[(long)r * 64 + c];
  }
  __shared__ float red[256];
  red[t] = sum;
  __syncthreads();
  if (t < 128) red[t] += red[t + 128];
  __syncthreads();
  if (t < 64) atomicAdd(&acc[c], red[t] + red[t + 64]);
}

__global__ void writeout_kernel(const float* __restrict__ acc,
                                const float* __restrict__ bm,
                                float* __restrict__ out) {
  int t = threadIdx.x;
  if (t < 64) {
    float x = acc[t] + bm[t];
    out[t] = 1.0f / (1.0f + expf(-x));
  }
}

// ---------------------------------------------------------------------------
extern "C" void kernel_launch(void* const* d_in, const int* in_sizes, int n_in,
                              void* d_out, int out_size, void* d_ws,
                              size_t ws_size, hipStream_t stream) {
  const float* emb  = (const float*)d_in[0];
  const float* W1   = (const float*)d_in[1];
  // d_in[2] = b1: cancels exactly under BN
  const float* g1   = (const float*)d_in[3];
  const float* be1  = (const float*)d_in[4];
  const float* W2   = (const float*)d_in[5];
  // d_in[6] = b2: cancels under BN
  const float* g2   = (const float*)d_in[7];
  const float* be2  = (const float*)d_in[8];
  const float* Wm   = (const float*)d_in[9];
  const float* bm   = (const float*)d_in[10];
  // d_in[11] = vertices = arange(N): identity gather
  const int* row    = (const int*)d_in[12];
  const int* col    = (const int*)d_in[13];
  const float* vals = (const float*)d_in[14];

  // workspace layout
  float*  h      = (float*)d_ws;               // 6,400,000 f (25.6 MB)
  ushort* sup    = (ushort*)(h + 6400000);     // 6,400,000 bf16 (12.8 MB)
  int2*   epack  = (int2*)(sup + 6400000);     // 1,600,000 int2 (12.8 MB)
  int*    rowptr = (int*)(epack + 1600000);    // 50,001
  int*    cursor = rowptr + 50001;             // 50,000
  int*    cnt    = cursor + 50000;             // 50,000
  int*    bsum   = cnt + 50000;                // 256
  int*    boff   = bsum + 256;                 // 256
  float*  s1     = (float*)(boff + 256);       // 128
  float*  ss1    = s1 + 128;                   // 128
  float*  s2     = ss1 + 128;                  // 64
  float*  ss2    = s2 + 64;                    // 64
  float*  acc    = ss2 + 64;                   // 64
  float*  out = (float*)d_out;

  const int NB = (N_NODES + 255) / 256;  // 196

  hipMemsetAsync(cnt, 0, N_NODES * sizeof(int), stream);
  hipMemsetAsync(s1, 0, 448 * sizeof(float), stream);

  // ---- CSR build ----
  hist_kernel<<<(NEDGE / 4 + 255) / 256, 256, 0, stream>>>(
      (const int4*)row, cnt);
  blocksum_kernel<<<NB, 256, 0, stream>>>(cnt, bsum);
  scanb_kernel<<<1, 256, 0, stream>>>(bsum, boff, NB);
  expand_kernel<<<NB, 256, 0, stream>>>(cnt, boff, rowptr, cursor);
  scatter_kernel<<<(NEDGE / 4 + 255) / 256, 256, 0, stream>>>(
      (const int4*)row, (const int4*)col, (const float4*)vals, cursor, epack);

  // ---- Layer 1 ----
  gemm1_kernel<<<1563, 256, 0, stream>>>((const float4*)emb,
                                         (const float4*)W1, sup);
  gather128_kernel<<<(N_NODES * 64 + 255) / 256, 256, 0, stream>>>(
      rowptr, epack, sup, (float2*)h);
  stats_kernel<128><<<512, 256, 0, stream>>>(h, s1, ss1);

  // ---- Layer 2 ----
  gemm2_kernel<<<1563, 256, 0, stream>>>((const float4*)h, (const float4*)W2,
                                         s1, ss1, g1, be1, sup);
  gather64_kernel<<<(N_NODES * 32 + 255) / 256, 256, 0, stream>>>(
      rowptr, epack, sup, (float2*)h);
  stats_kernel<64><<<512, 256, 0, stream>>>(h, s2, ss2);

  // ---- MaskLinear + sigmoid ----
  final_kernel<<<512, 256, 0, stream>>>(h, Wm, s2, ss2, g2, be2, acc);
  writeout_kernel<<<1, 64, 0, stream>>>(acc, bm, out);
}

// Round 4
// 456.142 us; speedup vs baseline: 9.2158x; 1.1863x over previous
//
#include <hip/hip_runtime.h>
#include <hip/hip_bf16.h>
#include <math.h>

#define N_NODES 50000
#define NEDGE 1600000
#define BN_EPS 1e-5f

__device__ inline float bf2f(ushort u) {
  union { unsigned i; float f; } v;
  v.i = ((unsigned)u) << 16;
  return v.f;
}
__device__ inline ushort f2bf(float x) {
  __hip_bfloat16 b = __float2bfloat16(x);
  return *(ushort*)&b;
}

// ---------------------------------------------------------------------------
// GEMM1: C[N,128](bf16) = X[N,128] @ W[128,128]   (f32 accum, VALU)
// ---------------------------------------------------------------------------
__global__ __launch_bounds__(256) void gemm1_kernel(
    const float4* __restrict__ X4, const float4* __restrict__ W4,
    ushort* __restrict__ C) {
  __shared__ float4 sW[64 * 32];   // 32KB
  __shared__ float4 sX[32 * 32];   // 16KB
  float* Xl = (float*)sX;
  const int t = threadIdx.x;
  const int r0 = blockIdx.x * 32;

  for (int i = t; i < 1024; i += 256) {
    int rr = i >> 5;
    int r = r0 + rr;
    sX[i] = (r < N_NODES) ? X4[(long)r * 32 + (i & 31)]
                          : make_float4(0.f, 0.f, 0.f, 0.f);
  }

  const int tx = t & 31;
  const int ty = t >> 5;
  float acc[4][4] = {{0.f}};

  for (int kt = 0; kt < 2; ++kt) {
    __syncthreads();
    for (int i = t; i < 2048; i += 256) sW[i] = W4[kt * 2048 + i];
    __syncthreads();
    const int kbase = kt * 64;
#pragma unroll 8
    for (int kk = 0; kk < 64; ++kk) {
      float4 wv = sW[kk * 32 + tx];
      float x0 = Xl[(ty * 4 + 0) * 128 + kbase + kk];
      float x1 = Xl[(ty * 4 + 1) * 128 + kbase + kk];
      float x2 = Xl[(ty * 4 + 2) * 128 + kbase + kk];
      float x3 = Xl[(ty * 4 + 3) * 128 + kbase + kk];
      acc[0][0] += x0 * wv.x; acc[0][1] += x0 * wv.y;
      acc[0][2] += x0 * wv.z; acc[0][3] += x0 * wv.w;
      acc[1][0] += x1 * wv.x; acc[1][1] += x1 * wv.y;
      acc[1][2] += x1 * wv.z; acc[1][3] += x1 * wv.w;
      acc[2][0] += x2 * wv.x; acc[2][1] += x2 * wv.y;
      acc[2][2] += x2 * wv.z; acc[2][3] += x2 * wv.w;
      acc[3][0] += x3 * wv.x; acc[3][1] += x3 * wv.y;
      acc[3][2] += x3 * wv.z; acc[3][3] += x3 * wv.w;
    }
  }
  for (int j = 0; j < 4; ++j) {
    int r = r0 + ty * 4 + j;
    if (r < N_NODES) {
      ushort4 o;
      o.x = f2bf(acc[j][0]); o.y = f2bf(acc[j][1]);
      o.z = f2bf(acc[j][2]); o.w = f2bf(acc[j][3]);
      *(ushort4*)&C[(long)r * 128 + tx * 4] = o;
    }
  }
}

// ---------------------------------------------------------------------------
// GEMM2: C[N,64](bf16) = relu(bn1(H[N,128])) @ W[128,64]
// ---------------------------------------------------------------------------
__global__ __launch_bounds__(256) void gemm2_kernel(
    const float4* __restrict__ H4, const float4* __restrict__ W4,
    const float* __restrict__ s1, const float* __restrict__ ss1,
    const float* __restrict__ gamma, const float* __restrict__ beta,
    ushort* __restrict__ C) {
  __shared__ float4 sW[128 * 16];  // 32KB
  __shared__ float4 sX[32 * 32];   // 16KB
  __shared__ float sA[128], sB[128];
  const int t = threadIdx.x;

  if (t < 128) {
    float mean = s1[t] * (1.0f / N_NODES);
    float var = ss1[t] * (1.0f / N_NODES) - mean * mean;
    float a = gamma[t] * rsqrtf(var + BN_EPS);
    sA[t] = a;
    sB[t] = beta[t] - a * mean;
  }
  for (int i = t; i < 2048; i += 256) sW[i] = W4[i];
  __syncthreads();

  const int r0 = blockIdx.x * 32;
  for (int i = t; i < 1024; i += 256) {
    int rr = i >> 5;
    int r = r0 + rr;
    int c4 = i & 31;
    float4 v = make_float4(0.f, 0.f, 0.f, 0.f);
    if (r < N_NODES) {
      v = H4[(long)r * 32 + c4];
      float4 a4 = *(const float4*)&sA[c4 * 4];
      float4 b4 = *(const float4*)&sB[c4 * 4];
      v.x = fmaxf(a4.x * v.x + b4.x, 0.f);
      v.y = fmaxf(a4.y * v.y + b4.y, 0.f);
      v.z = fmaxf(a4.z * v.z + b4.z, 0.f);
      v.w = fmaxf(a4.w * v.w + b4.w, 0.f);
    }
    sX[i] = v;
  }
  __syncthreads();

  const int tx = t & 15;
  const int ty = t >> 4;
  float acc[2][4] = {{0.f}};
  float* Xl = (float*)sX;
#pragma unroll 8
  for (int k = 0; k < 128; ++k) {
    float4 wv = sW[k * 16 + tx];
    float x0 = Xl[(ty * 2 + 0) * 128 + k];
    float x1 = Xl[(ty * 2 + 1) * 128 + k];
    acc[0][0] += x0 * wv.x; acc[0][1] += x0 * wv.y;
    acc[0][2] += x0 * wv.z; acc[0][3] += x0 * wv.w;
    acc[1][0] += x1 * wv.x; acc[1][1] += x1 * wv.y;
    acc[1][2] += x1 * wv.z; acc[1][3] += x1 * wv.w;
  }
  for (int j = 0; j < 2; ++j) {
    int r = r0 + ty * 2 + j;
    if (r < N_NODES) {
      ushort4 o;
      o.x = f2bf(acc[j][0]); o.y = f2bf(acc[j][1]);
      o.z = f2bf(acc[j][2]); o.w = f2bf(acc[j][3]);
      *(ushort4*)&C[(long)r * 64 + tx * 4] = o;
    }
  }
}

// ---------------------------------------------------------------------------
// CSR build: rank (atomic hist + stable rank) -> scan -> place (no atomics)
// ---------------------------------------------------------------------------
__global__ __launch_bounds__(256) void rank_kernel(
    const int4* __restrict__ row4, int* __restrict__ cnt,
    ushort* __restrict__ rank) {
  int i = blockIdx.x * 256 + threadIdx.x;
  if (i >= NEDGE / 4) return;
  int4 r = row4[i];
  ushort4 rk;
  rk.x = (ushort)atomicAdd(&cnt[r.x], 1);
  rk.y = (ushort)atomicAdd(&cnt[r.y], 1);
  rk.z = (ushort)atomicAdd(&cnt[r.z], 1);
  rk.w = (ushort)atomicAdd(&cnt[r.w], 1);
  ((ushort4*)rank)[i] = rk;
}

__global__ __launch_bounds__(256) void blocksum_kernel(
    const int* __restrict__ cnt, int* __restrict__ bsum) {
  int idx = blockIdx.x * 256 + threadIdx.x;
  int v = (idx < N_NODES) ? cnt[idx] : 0;
  __shared__ int sc[256];
  sc[threadIdx.x] = v;
  __syncthreads();
  for (int off = 128; off > 0; off >>= 1) {
    if (threadIdx.x < off) sc[threadIdx.x] += sc[threadIdx.x + off];
    __syncthreads();
  }
  if (threadIdx.x == 0) bsum[blockIdx.x] = sc[0];
}

__global__ __launch_bounds__(256) void scanb_kernel(
    const int* __restrict__ bsum, int* __restrict__ boff, int nb) {
  int t = threadIdx.x;
  int v = (t < nb) ? bsum[t] : 0;
  __shared__ int sc[256];
  sc[t] = v;
  __syncthreads();
  for (int off = 1; off < 256; off <<= 1) {
    int x = (t >= off) ? sc[t - off] : 0;
    __syncthreads();
    sc[t] += x;
    __syncthreads();
  }
  if (t < nb) boff[t] = sc[t] - v;  // exclusive
}

__global__ __launch_bounds__(256) void expand_kernel(
    const int* __restrict__ cnt, const int* __restrict__ boff,
    int* __restrict__ rowptr) {
  int t = threadIdx.x;
  int idx = blockIdx.x * 256 + t;
  int v = (idx < N_NODES) ? cnt[idx] : 0;
  __shared__ int sc[256];
  sc[t] = v;
  __syncthreads();
  for (int off = 1; off < 256; off <<= 1) {
    int x = (t >= off) ? sc[t - off] : 0;
    __syncthreads();
    sc[t] += x;
    __syncthreads();
  }
  if (idx < N_NODES) rowptr[idx] = boff[blockIdx.x] + sc[t] - v;
  if (idx == 0) rowptr[N_NODES] = NEDGE;
}

// place: ep[rowptr[row]+rank] = (col<<16) | bf16(val)   — no atomics
__global__ __launch_bounds__(256) void place_kernel(
    const int4* __restrict__ row4, const int4* __restrict__ col4,
    const float4* __restrict__ vals4, const ushort* __restrict__ rank,
    const int* __restrict__ rowptr, unsigned* __restrict__ ep) {
  int i = blockIdx.x * 256 + threadIdx.x;
  if (i >= NEDGE / 4) return;
  int4 r = row4[i];
  int4 c = col4[i];
  float4 v = vals4[i];
  ushort4 rk = ((const ushort4*)rank)[i];
  ep[rowptr[r.x] + rk.x] = ((unsigned)c.x << 16) | f2bf(v.x);
  ep[rowptr[r.y] + rk.y] = ((unsigned)c.y << 16) | f2bf(v.y);
  ep[rowptr[r.z] + rk.z] = ((unsigned)c.z << 16) | f2bf(v.z);
  ep[rowptr[r.w] + rk.w] = ((unsigned)c.w << 16) | f2bf(v.w);
}

// ---------------------------------------------------------------------------
// Gather-SpMM, 128 feats (bf16 source): one wave per row, ushort2/lane.
// ---------------------------------------------------------------------------
__global__ __launch_bounds__(256) void gather128_kernel(
    const int* __restrict__ rowptr, const unsigned* __restrict__ ep,
    const ushort* __restrict__ S, float2* __restrict__ H) {
  int r = (blockIdx.x * 256 + threadIdx.x) >> 6;
  int lane = threadIdx.x & 63;
  if (r >= N_NODES) return;
  int b = rowptr[r], e2 = rowptr[r + 1];
  float a0x = 0.f, a0y = 0.f, a1x = 0.f, a1y = 0.f;
  int e = b;
  for (; e + 1 < e2; e += 2) {
    unsigned u0 = ep[e];
    unsigned u1 = ep[e + 1];
    float v0 = __int_as_float((int)(u0 << 16));
    float v1 = __int_as_float((int)(u1 << 16));
    ushort2 s0 = ((const ushort2*)(S + (long)(u0 >> 16) * 128))[lane];
    ushort2 s1 = ((const ushort2*)(S + (long)(u1 >> 16) * 128))[lane];
    a0x += v0 * bf2f(s0.x); a0y += v0 * bf2f(s0.y);
    a1x += v1 * bf2f(s1.x); a1y += v1 * bf2f(s1.y);
  }
  if (e < e2) {
    unsigned u0 = ep[e];
    float v0 = __int_as_float((int)(u0 << 16));
    ushort2 s0 = ((const ushort2*)(S + (long)(u0 >> 16) * 128))[lane];
    a0x += v0 * bf2f(s0.x); a0y += v0 * bf2f(s0.y);
  }
  H[(long)r * 64 + lane] = make_float2(a0x + a1x, a0y + a1y);
}

// ---------------------------------------------------------------------------
// Gather-SpMM, 64 feats (bf16 source): half-wave per row, ushort2/lane.
// ---------------------------------------------------------------------------
__global__ __launch_bounds__(256) void gather64_kernel(
    const int* __restrict__ rowptr, const unsigned* __restrict__ ep,
    const ushort* __restrict__ S, float2* __restrict__ H) {
  int r = (blockIdx.x * 256 + threadIdx.x) >> 5;
  int sub = threadIdx.x & 31;
  if (r >= N_NODES) return;
  int b = rowptr[r], e2 = rowptr[r + 1];
  float a0x = 0.f, a0y = 0.f, a1x = 0.f, a1y = 0.f;
  int e = b;
  for (; e + 1 < e2; e += 2) {
    unsigned u0 = ep[e];
    unsigned u1 = ep[e + 1];
    float v0 = __int_as_float((int)(u0 << 16));
    float v1 = __int_as_float((int)(u1 << 16));
    ushort2 s0 = ((const ushort2*)(S + (long)(u0 >> 16) * 64))[sub];
    ushort2 s1 = ((const ushort2*)(S + (long)(u1 >> 16) * 64))[sub];
    a0x += v0 * bf2f(s0.x); a0y += v0 * bf2f(s0.y);
    a1x += v1 * bf2f(s1.x); a1y += v1 * bf2f(s1.y);
  }
  if (e < e2) {
    unsigned u0 = ep[e];
    float v0 = __int_as_float((int)(u0 << 16));
    ushort2 s0 = ((const ushort2*)(S + (long)(u0 >> 16) * 64))[sub];
    a0x += v0 * bf2f(s0.x); a0y += v0 * bf2f(s0.y);
  }
  H[(long)r * 32 + sub] = make_float2(a0x + a1x, a0y + a1y);
}

// ---------------------------------------------------------------------------
// Column stats over f32 H
// ---------------------------------------------------------------------------
template <int NF>
__global__ __launch_bounds__(256) void stats_kernel(
    const float* __restrict__ H, float* __restrict__ s,
    float* __restrict__ ss) {
  const int t = threadIdx.x;
  const int c = t & (NF - 1);
  const int rg = t / NF;
  const int RG = 256 / NF;
  float sum = 0.f, sq = 0.f;
  for (int r = blockIdx.x * RG + rg; r < N_NODES; r += gridDim.x * RG) {
    float x = H[(long)r * NF + c];
    sum += x;
    sq += x * x;
  }
  atomicAdd(&s[c], sum);
  atomicAdd(&ss[c], sq);
}

// ---------------------------------------------------------------------------
// Final: acc[c] += sum_r relu(bn2(H2[r][c])) * Wm[r][c]
// ---------------------------------------------------------------------------
__global__ __launch_bounds__(256) void final_kernel(
    const float* __restrict__ H, const float* __restrict__ Wm,
    const float* __restrict__ s2, const float* __restrict__ ss2,
    const float* __restrict__ gamma, const float* __restrict__ beta,
    float* __restrict__ acc) {
  const int t = threadIdx.x;
  const int c = t & 63;
  const int rg = t >> 6;
  float mean = s2[c] * (1.0f / N_NODES);
  float var = ss2[c] * (1.0f / N_NODES) - mean * mean;
  float a = gamma[c] * rsqrtf(var + BN_EPS);
  float b = beta[c] - a * mean;
  float sum = 0.f;
  for (int r = blockIdx.x * 4 + rg; r < N_NODES; r += gridDim.x * 4) {
    float x = fmaxf(a * H[(long)r * 64 + c] + b, 0.f);
    sum += x * Wm[(long)r * 64 + c];
  }
  __shared__ float red[256];
  red[t] = sum;
  __syncthreads();
  if (t < 128) red[t] += red[t + 128];
  __syncthreads();
  if (t < 64) atomicAdd(&acc[c], red[t] + red[t + 64]);
}

__global__ void writeout_kernel(const float* __restrict__ acc,
                                const float* __restrict__ bm,
                                float* __restrict__ out) {
  int t = threadIdx.x;
  if (t < 64) {
    float x = acc[t] + bm[t];
    out[t] = 1.0f / (1.0f + expf(-x));
  }
}

// ---------------------------------------------------------------------------
extern "C" void kernel_launch(void* const* d_in, const int* in_sizes, int n_in,
                              void* d_out, int out_size, void* d_ws,
                              size_t ws_size, hipStream_t stream) {
  const float* emb  = (const float*)d_in[0];
  const float* W1   = (const float*)d_in[1];
  // d_in[2] = b1: cancels exactly under BN
  const float* g1   = (const float*)d_in[3];
  const float* be1  = (const float*)d_in[4];
  const float* W2   = (const float*)d_in[5];
  // d_in[6] = b2: cancels under BN
  const float* g2   = (const float*)d_in[7];
  const float* be2  = (const float*)d_in[8];
  const float* Wm   = (const float*)d_in[9];
  const float* bm   = (const float*)d_in[10];
  // d_in[11] = vertices = arange(N): identity gather
  const int* row    = (const int*)d_in[12];
  const int* col    = (const int*)d_in[13];
  const float* vals = (const float*)d_in[14];

  // workspace layout
  float*    h      = (float*)d_ws;               // 6,400,000 f (25.6 MB)
  ushort*   sup    = (ushort*)(h + 6400000);     // 6,400,000 bf16 (12.8 MB)
  unsigned* ep     = (unsigned*)(sup + 6400000); // 1,600,000 u32 (6.4 MB)
  ushort*   rank   = (ushort*)(ep + 1600000);    // 1,600,000 u16 (3.2 MB)
  int*      rowptr = (int*)(rank + 1600000);     // 50,001
  int*      cnt    = rowptr + 50001;             // 50,000
  int*      bsum   = cnt + 50000;                // 256
  int*      boff   = bsum + 256;                 // 256
  float*    s1     = (float*)(boff + 256);       // 128
  float*    ss1    = s1 + 128;                   // 128
  float*    s2     = ss1 + 128;                  // 64
  float*    ss2    = s2 + 64;                    // 64
  float*    acc    = ss2 + 64;                   // 64
  float*    out = (float*)d_out;

  const int NB = (N_NODES + 255) / 256;  // 196
  const int EB = (NEDGE / 4 + 255) / 256;

  hipMemsetAsync(cnt, 0, N_NODES * sizeof(int), stream);
  hipMemsetAsync(s1, 0, 448 * sizeof(float), stream);

  // ---- CSR build ----
  rank_kernel<<<EB, 256, 0, stream>>>((const int4*)row, cnt, rank);
  blocksum_kernel<<<NB, 256, 0, stream>>>(cnt, bsum);
  scanb_kernel<<<1, 256, 0, stream>>>(bsum, boff, NB);
  expand_kernel<<<NB, 256, 0, stream>>>(cnt, boff, rowptr);
  place_kernel<<<EB, 256, 0, stream>>>((const int4*)row, (const int4*)col,
                                       (const float4*)vals, rank, rowptr, ep);

  // ---- Layer 1 ----
  gemm1_kernel<<<1563, 256, 0, stream>>>((const float4*)emb,
                                         (const float4*)W1, sup);
  gather128_kernel<<<(N_NODES * 64 + 255) / 256, 256, 0, stream>>>(
      rowptr, ep, sup, (float2*)h);
  stats_kernel<128><<<512, 256, 0, stream>>>(h, s1, ss1);

  // ---- Layer 2 ----
  gemm2_kernel<<<1563, 256, 0, stream>>>((const float4*)h, (const float4*)W2,
                                         s1, ss1, g1, be1, sup);
  gather64_kernel<<<(N_NODES * 32 + 255) / 256, 256, 0, stream>>>(
      rowptr, ep, sup, (float2*)h);
  stats_kernel<64><<<512, 256, 0, stream>>>(h, s2, ss2);

  // ---- MaskLinear + sigmoid ----
  final_kernel<<<512, 256, 0, stream>>>(h, Wm, s2, ss2, g2, be2, acc);
  writeout_kernel<<<1, 64, 0, stream>>>(acc, bm, out);
}